// Round 5
// baseline (1424.336 us; speedup 1.0000x reference)
//
#include <hip/hip_runtime.h>
#include <cstdint>
#include <cstddef>

#define HD    1024
#define SLOTS 272
#define MEMS  256
#define BATCH 8
#define TT    4096
#define RR    (BATCH*TT)
#define RANKC 10

#define GAMMA 0.92f
#define BETA  0.08f
#define PTS   0.4f

// Workspace int-block layout (at cbuf + 2064 floats):
//   I[0..1]    : eps/pred any-nonzero flags
//   I[8..519]  : mflag[512]  -- per proj tile (tc*8 + b), 64 rows each
//   I[520..527]: sprog[8]    -- valid W row prefix per batch
//   I[528]     : outp ticket    I[529]: proj ticket
#define I_MFLAG   8
#define I_SPROG   520
#define I_TICKO   528
#define I_TICKP   529
#define SPIN_BOUND (1 << 20)   // ~100x worst legit wait; bail -> miscompare, not hang

typedef float f32x2 __attribute__((ext_vector_type(2)));
#define PKFMA(a, b, c) __builtin_elementwise_fma((a), (b), (c))

// ---------------------------------------------------------------------------
// DPP wave64 sum-allreduce: 6 VALU-speed cross-lane adds + readlane broadcast.
// ---------------------------------------------------------------------------
#define DPP_ADD(v, ctrl, rmask)                                                   \
    v += __int_as_float(__builtin_amdgcn_update_dpp(                              \
        0, __float_as_int(v), (ctrl), (rmask), 0xf, true))

__device__ __forceinline__ float wave_sum_bcast(float v)
{
    DPP_ADD(v, 0xB1,  0xf);
    DPP_ADD(v, 0x4E,  0xf);
    DPP_ADD(v, 0x141, 0xf);
    DPP_ADD(v, 0x140, 0xf);
    DPP_ADD(v, 0x142, 0xa);
    DPP_ADD(v, 0x143, 0xc);
    return __int_as_float(__builtin_amdgcn_readlane(__float_as_int(v), 63));
}

// ---------------------------------------------------------------------------
// prep: per-slot constants + zero the sync block.
// ---------------------------------------------------------------------------
__global__ void prep_kernel(const float* __restrict__ t0re, const float* __restrict__ t0im,
                            const float* __restrict__ eta_raw,
                            const float* __restrict__ trot, const float* __restrict__ w_r,
                            const float* __restrict__ bgate,
                            const float* __restrict__ eps_scale, const float* __restrict__ pred_scale,
                            const float* __restrict__ eps_diag, const float* __restrict__ pred_diag,
                            float* __restrict__ consts, int* __restrict__ I)
{
    __shared__ float red[MEMS];
    const int s = threadIdx.x;  // 256 threads
    for (int i = s; i < 544; i += 256) I[i] = 0;   // flags+mflag+sprog+tickets
    const float tr = t0re[s], ti = t0im[s];
    red[s] = tr * tr + ti * ti;
    __syncthreads();
    for (int off = 128; off > 0; off >>= 1) {
        if (s < off) red[s] += red[s + off];
        __syncthreads();
    }
    const float nrm = sqrtf(fmaxf(red[0], 1e-16f));
    const float eta = log1pf(expf(eta_raw[0]));
    const float rc = cosf(trot[s]), rs = sinf(trot[s]);
    const float c1 = GAMMA + eta * eps_diag[s];
    const float c2 = PTS * pred_diag[s];
    consts[0 * MEMS + s] = 1.0f / (1.0f + expf(-w_r[s]));
    consts[1 * MEMS + s] = 1.0f / (1.0f + expf(-bgate[s]));
    consts[2 * MEMS + s] = c1 * rc - c2 * rs;   // A
    consts[3 * MEMS + s] = c1 * rs + c2 * rc;   // B
    consts[4 * MEMS + s] = tr / nrm;
    consts[5 * MEMS + s] = ti / nrm;
    consts[6 * MEMS + s] = rc;
    consts[7 * MEMS + s] = rs;
    if (s == 0) {
        consts[8 * MEMS] = eta;
        int f1 = 0, f2 = 0;
        for (int k = 0; k < RANKC; ++k) {
            if (eps_scale[k]  != 0.0f) f1 = 1;
            if (pred_scale[k] != 0.0f) f2 = 1;
        }
        I[0] = f1;
        I[1] = f2;
    }
}

// ---------------------------------------------------------------------------
// proj tile (64 rows x full 256 cols) + FUSED top-8 mask + flag release.
// Row owned by the 32 contiguous lanes sharing mt (a half-wave: shfl_xor
// off<=16 stays inside it).  Same dup-counting semantics as the verified
// standalone topk kernel.
// ---------------------------------------------------------------------------
__device__ __forceinline__ void proj_topk_tile(int b, int tc,
    const float* __restrict__ x, const float* __restrict__ basis,
    float* __restrict__ M, int* __restrict__ I, int flagidx)
{
    __shared__ float pAs[16][64];
    __shared__ float pBs[16][260];
    const int tid  = threadIdx.x;
    const size_t row0 = (size_t)b * TT + (size_t)tc * 64;
    const int mt = tid >> 5;        // 0..7
    const int nt = tid & 31;        // 0..31
    const int ar = tid >> 2;        // 0..63
    const int ak = (tid & 3) * 4;
    const int bk = tid >> 4;        // 0..15
    const int bn = (tid & 15) * 16;
    float acc[2][2][4][4] = {};
    for (int k0 = 0; k0 < HD; k0 += 16) {
        {
            const float4 av = *(const float4*)&x[(row0 + ar) * HD + k0 + ak];
            pAs[ak + 0][ar] = av.x; pAs[ak + 1][ar] = av.y;
            pAs[ak + 2][ar] = av.z; pAs[ak + 3][ar] = av.w;
#pragma unroll
            for (int c = 0; c < 4; ++c) {
                const float4 bv = *(const float4*)&basis[(size_t)(k0 + bk) * SLOTS + bn + c * 4];
                *(float4*)&pBs[bk][bn + c * 4] = bv;
            }
        }
        __syncthreads();
#pragma unroll
        for (int kk = 0; kk < 16; ++kk) {
            const float4 a0 = *(const float4*)&pAs[kk][mt * 4];
            const float4 a1 = *(const float4*)&pAs[kk][32 + mt * 4];
            const float4 b0 = *(const float4*)&pBs[kk][nt * 4];
            const float4 b1 = *(const float4*)&pBs[kk][128 + nt * 4];
            const float av[2][4] = {{a0.x, a0.y, a0.z, a0.w}, {a1.x, a1.y, a1.z, a1.w}};
            const float bv[2][4] = {{b0.x, b0.y, b0.z, b0.w}, {b1.x, b1.y, b1.z, b1.w}};
#pragma unroll
            for (int p = 0; p < 2; ++p)
#pragma unroll
                for (int q = 0; q < 2; ++q)
#pragma unroll
                    for (int i = 0; i < 4; ++i)
#pragma unroll
                        for (int j = 0; j < 4; ++j)
                            acc[p][q][i][j] += av[p][i] * bv[q][j];
        }
        __syncthreads();
    }
#pragma unroll
    for (int p = 0; p < 2; ++p)
#pragma unroll
        for (int i = 0; i < 4; ++i) {
            float v[8], a[8], w8[8];
#pragma unroll
            for (int q = 0; q < 2; ++q)
#pragma unroll
                for (int j = 0; j < 4; ++j) {
                    v[q * 4 + j] = acc[p][q][i][j];
                    a[q * 4 + j] = fabsf(v[q * 4 + j]);
                    w8[q * 4 + j] = a[q * 4 + j];
                }
            float kv = 0.0f;
#pragma unroll
            for (int it = 0; it < 8; ++it) {
                float lm = w8[0]; int li = 0;
#pragma unroll
                for (int e = 1; e < 8; ++e)
                    if (w8[e] > lm) { lm = w8[e]; li = e; }
                float bm = lm; int bi = nt * 8 + li;
#pragma unroll
                for (int off = 1; off < 32; off <<= 1) {
                    float om = __shfl_xor(bm, off);
                    int   oi = __shfl_xor(bi, off);
                    if (om > bm || (om == bm && oi < bi)) { bm = om; bi = oi; }
                }
                kv = bm;
                if ((bi >> 3) == nt) w8[bi & 7] = -1.0f;
            }
            const int r = p * 32 + mt * 4 + i;
#pragma unroll
            for (int q = 0; q < 2; ++q) {
                float4 o;
                o.x = (a[q * 4 + 0] >= kv) ? BETA * v[q * 4 + 0] : 0.0f;
                o.y = (a[q * 4 + 1] >= kv) ? BETA * v[q * 4 + 1] : 0.0f;
                o.z = (a[q * 4 + 2] >= kv) ? BETA * v[q * 4 + 2] : 0.0f;
                o.w = (a[q * 4 + 3] >= kv) ? BETA * v[q * 4 + 3] : 0.0f;
                *(float4*)&M[(row0 + r) * MEMS + q * 128 + nt * 4] = o;
            }
        }
    __threadfence();      // each thread drains its own M stores (device scope)
    __syncthreads();
    if (tid == 0)
        __hip_atomic_store(&I[flagidx], 1, __ATOMIC_RELEASE, __HIP_MEMORY_SCOPE_AGENT);
}

// ---------------------------------------------------------------------------
// gating helpers (bounded spins: bail -> garbage -> miscompare, never hang).
// ---------------------------------------------------------------------------
__device__ __forceinline__ int poll_rows(int* __restrict__ mflag, int b, int fp, int need)
{
    if (need > TT - 1) need = TT - 1;
    int guard = 0;
    while (fp <= need) {
        if (__hip_atomic_load(&mflag[((fp >> 6) << 3) + b],
                              __ATOMIC_ACQUIRE, __HIP_MEMORY_SCOPE_AGENT)) {
            fp += 64;
        } else {
            __builtin_amdgcn_s_sleep(16);
            if (++guard > SPIN_BOUND) { fp = need + 1; break; }
        }
    }
    return fp;
}

__device__ __forceinline__ void publish_rows(int* __restrict__ sprog, int b, int rows, int lane)
{
    __threadfence();
    if (lane == 0)
        __hip_atomic_store(&sprog[b], rows, __ATOMIC_RELEASE, __HIP_MEMORY_SCOPE_AGENT);
}

// ---------------------------------------------------------------------------
// scan role: one wave per batch.  R2-exact deferred-norm fast path (measured
// 392us; issue-bound minimum of tried formulations).  Gated on mflag;
// publishes valid-row count every 128 steps (value = rows written, verified
// off-by-one-free: after inner t0 block, rows 0..t0+14 written = t0+15).
// setprio(3): wins SIMD arbitration over co-resident worker waves.
// ---------------------------------------------------------------------------
__device__ __forceinline__ void scan_role(int b,
    const float* __restrict__ M, const float* __restrict__ consts,
    int* __restrict__ I,
    const float* __restrict__ eps_fac, const float* __restrict__ eps_scale,
    const float* __restrict__ eps_diag,
    const float* __restrict__ pred_fac, const float* __restrict__ pred_scale,
    const float* __restrict__ pred_diag,
    float* __restrict__ Wout)
{
    __builtin_amdgcn_s_setprio(3);
    const int lane = threadIdx.x & 63;
    const int s0   = lane * 4;
    const int general = I[0] | I[1];
    const size_t base = (size_t)b * TT * MEMS + s0;
    int* mflag = I + I_MFLAG;
    int* sprog = I + I_SPROG;
    int fp = 0;

    if (!general) {
        // ---------------- FAST PATH (R2 deferred norm, verbatim) ----------------
        f32x2 wrg[2], A2[2], B2[2];
        f32x2 wre[2], wim[2], qre[2], qim[2];
        {
            const float4 w4 = *(const float4*)&consts[0 * MEMS + s0];
            const float4 a4 = *(const float4*)&consts[2 * MEMS + s0];
            const float4 b4 = *(const float4*)&consts[3 * MEMS + s0];
            const float4 r4 = *(const float4*)&consts[4 * MEMS + s0];
            const float4 i4 = *(const float4*)&consts[5 * MEMS + s0];
            wrg[0] = {w4.x, w4.y};  wrg[1] = {w4.z, w4.w};
            A2[0]  = {a4.x, a4.y};  A2[1]  = {a4.z, a4.w};
            B2[0]  = {b4.x, b4.y};  B2[1]  = {b4.z, b4.w};
            wre[0] = {r4.x, r4.y};  wre[1] = {r4.z, r4.w};
            wim[0] = {i4.x, i4.y};  wim[1] = {i4.z, i4.w};
            qre[0] = wre[0]; qre[1] = wre[1];
            qim[0] = wim[0]; qim[1] = wim[1];
        }
        float ssp;
        {
            const f32x2 p0 = PKFMA(wim[0], wim[0], wre[0] * wre[0]);
            const f32x2 p1 = PKFMA(wim[1], wim[1], wre[1] * wre[1]);
            const f32x2 pp = p0 + p1;
            ssp = pp.x + pp.y;
        }
        fp = poll_rows(mflag, b, fp, 31);
        float4 mbuf[16];
#pragma unroll
        for (int j = 0; j < 16; ++j)
            mbuf[j] = *(const float4*)&M[base + (size_t)j * MEMS];
        for (int t0 = 0; t0 < TT; t0 += 16) {
            if (t0 + 31 >= fp) fp = poll_rows(mflag, b, fp, t0 + 31);
#pragma unroll
            for (int j = 0; j < 16; ++j) {
                const int t = t0 + j;
                const float4 mc = mbuf[j];
                const int pft = (t + 16 < TT) ? (t + 16) : (TT - 1);  // gated range
                mbuf[j] = *(const float4*)&M[base + (size_t)pft * MEMS];
                const float stot = wave_sum_bcast(ssp);
                const float icv  = __builtin_amdgcn_rsqf(fmaxf(stot, 1e-16f));
                const f32x2 ic2  = {icv, icv};
                const f32x2 Lr0 = PKFMA(A2[0], wre[0], -(B2[0] * wim[0]));
                const f32x2 Li0 = PKFMA(B2[0], wre[0],  A2[0] * wim[0]);
                const f32x2 Lr1 = PKFMA(A2[1], wre[1], -(B2[1] * wim[1]));
                const f32x2 Li1 = PKFMA(B2[1], wre[1],  A2[1] * wim[1]);
                const f32x2 m0 = {mc.x, mc.y};
                const f32x2 m1 = {mc.z, mc.w};
                const f32x2 Wr0 = PKFMA(wrg[0], qre[0], m0);
                const f32x2 Wi0 = wrg[0] * qim[0];
                const f32x2 Wr1 = PKFMA(wrg[1], qre[1], m1);
                const f32x2 Wi1 = wrg[1] * qim[1];
                const f32x2 u1r0 = PKFMA(ic2, Lr0, Wr0);
                const f32x2 u1i0 = PKFMA(ic2, Li0, Wi0);
                const f32x2 u1r1 = PKFMA(ic2, Lr1, Wr1);
                const f32x2 u1i1 = PKFMA(ic2, Li1, Wi1);
                const f32x2 ps0 = PKFMA(u1i0, u1i0, u1r0 * u1r0);
                const f32x2 ps1 = PKFMA(u1i1, u1i1, u1r1 * u1r1);
                const f32x2 pp  = ps0 + ps1;
                const f32x2 nr0 = wre[0] * ic2, ni0 = wim[0] * ic2;
                const f32x2 nr1 = wre[1] * ic2, ni1 = wim[1] * ic2;
                const int trow = t ? (t - 1) : 0;
                const float4 st4 = {nr0.x, nr0.y, nr1.x, nr1.y};
                *(float4*)&Wout[base + (size_t)trow * MEMS] = st4;
                qre[0] = nr0;  qim[0] = ni0;  qre[1] = nr1;  qim[1] = ni1;
                wre[0] = u1r0; wim[0] = u1i0; wre[1] = u1r1; wim[1] = u1i1;
                ssp = pp.x + pp.y;
            }
            if (((t0 + 16) & 127) == 0) publish_rows(sprog, b, t0 + 15, lane);
        }
        {
            const float stot = wave_sum_bcast(ssp);
            const float icv  = __builtin_amdgcn_rsqf(fmaxf(stot, 1e-16f));
            const float4 wq4 = {wre[0].x * icv, wre[0].y * icv,
                                wre[1].x * icv, wre[1].y * icv};
            *(float4*)&Wout[base + (size_t)(TT - 1) * MEMS] = wq4;
        }
        publish_rows(sprog, b, TT, lane);
        return;
    }

    // ---------------- GENERAL PATH (R2 verbatim + gating) ----------------
    float wr4[4], ur[4], ui[4], pr[4], pi[4];
    float rc4[4], rs4[4], ed4[4], pd4[4];
#pragma unroll
    for (int i = 0; i < 4; ++i) {
        wr4[i] = consts[0 * MEMS + s0 + i];
        ur[i]  = consts[4 * MEMS + s0 + i];
        ui[i]  = consts[5 * MEMS + s0 + i];
        pr[i] = ur[i]; pi[i] = ui[i];
        rc4[i] = consts[6 * MEMS + s0 + i];
        rs4[i] = consts[7 * MEMS + s0 + i];
        ed4[i] = eps_diag[s0 + i];
        pd4[i] = pred_diag[s0 + i];
    }
    const float eta  = consts[8 * MEMS];
    const int es_any = I[0];
    const int ps_any = I[1];
    fp = poll_rows(mflag, b, fp, 7);
    float4 mbuf[4];
#pragma unroll
    for (int j = 0; j < 4; ++j)
        mbuf[j] = *(const float4*)&M[base + (size_t)j * MEMS];
    for (int t0 = 0; t0 < TT; t0 += 4) {
        if (t0 + 7 >= fp) fp = poll_rows(mflag, b, fp, t0 + 7);
#pragma unroll
        for (int j = 0; j < 4; ++j) {
            const int t = t0 + j;
            const float4 mc = mbuf[j];
            const int pft = (t + 4 < TT) ? (t + 4) : (TT - 1);
            mbuf[j] = *(const float4*)&M[base + (size_t)pft * MEMS];
            float rr[4], ri[4], nr[4], ni[4];
#pragma unroll
            for (int i = 0; i < 4; ++i) {
                rr[i] = ur[i] * rc4[i] - ui[i] * rs4[i];
                ri[i] = ur[i] * rs4[i] + ui[i] * rc4[i];
            }
            const float mv[4] = {mc.x, mc.y, mc.z, mc.w};
#pragma unroll
            for (int i = 0; i < 4; ++i) {
                nr[i] = GAMMA * rr[i] + wr4[i] * pr[i] + eta * ed4[i] * rr[i]
                        - PTS * pd4[i] * ri[i] + mv[i];
                ni[i] = GAMMA * ri[i] + wr4[i] * pi[i] + eta * ed4[i] * ri[i]
                        + PTS * pd4[i] * rr[i];
            }
            if (es_any) {
#pragma unroll
                for (int k = 0; k < RANKC; ++k) {
                    float u[4], prj = 0.0f, pij = 0.0f;
#pragma unroll
                    for (int i = 0; i < 4; ++i) {
                        u[i] = eps_fac[(size_t)(s0 + i) * RANKC + k];
                        prj = fmaf(u[i], rr[i], prj);
                        pij = fmaf(u[i], ri[i], pij);
                    }
                    prj = wave_sum_bcast(prj);
                    pij = wave_sum_bcast(pij);
                    const float sc = eta * eps_scale[k];
#pragma unroll
                    for (int i = 0; i < 4; ++i) {
                        nr[i] = fmaf(sc * u[i], prj, nr[i]);
                        ni[i] = fmaf(sc * u[i], pij, ni[i]);
                    }
                }
            }
            if (ps_any) {
#pragma unroll
                for (int k = 0; k < RANKC; ++k) {
                    float u[4], qrj = 0.0f, qij = 0.0f;
#pragma unroll
                    for (int i = 0; i < 4; ++i) {
                        u[i] = pred_fac[(size_t)(s0 + i) * RANKC + k];
                        qrj = fmaf(u[i], rr[i], qrj);
                        qij = fmaf(u[i], ri[i], qij);
                    }
                    qrj = wave_sum_bcast(qrj);
                    qij = wave_sum_bcast(qij);
                    const float sc = PTS * pred_scale[k];
#pragma unroll
                    for (int i = 0; i < 4; ++i) {
                        nr[i] = fmaf(-sc * u[i], qij, nr[i]);
                        ni[i] = fmaf( sc * u[i], qrj, ni[i]);
                    }
                }
            }
            float ss = 0.0f;
#pragma unroll
            for (int i = 0; i < 4; ++i) ss = fmaf(nr[i], nr[i], fmaf(ni[i], ni[i], ss));
            ss = wave_sum_bcast(ss);
            const float inv = __builtin_amdgcn_rsqf(fmaxf(ss, 1e-16f));
#pragma unroll
            for (int i = 0; i < 4; ++i) {
                pr[i] = ur[i]; pi[i] = ui[i];
                ur[i] = nr[i] * inv; ui[i] = ni[i] * inv;
            }
            const float4 wq = {ur[0], ur[1], ur[2], ur[3]};
            *(float4*)&Wout[base + (size_t)t * MEMS] = wq;
        }
        if (((t0 + 4) & 127) == 0) publish_rows(sprog, b, t0 + 4, lane);
    }
    publish_rows(sprog, b, TT, lane);
}

// ---------------------------------------------------------------------------
// outp tile (64 rows x 256 cols), gated on sprog[b] (bounded spin).
// ---------------------------------------------------------------------------
__device__ __forceinline__ void outp_tile(int tc, int b, int col,
    const float* __restrict__ W, const float* __restrict__ basis,
    const float* __restrict__ x, const float* __restrict__ alpha_p,
    const float* __restrict__ consts, int* __restrict__ I,
    float* __restrict__ y)
{
    __shared__ float oAs[16][64];
    __shared__ float oBs[16][260];
    const int tid = threadIdx.x;
    if (tid == 0) {
        int* sprog = I + I_SPROG;
        int guard = 0;
        while (__hip_atomic_load(&sprog[b], __ATOMIC_ACQUIRE,
                                 __HIP_MEMORY_SCOPE_AGENT) < tc * 64 + 64) {
            __builtin_amdgcn_s_sleep(32);
            if (++guard > SPIN_BOUND) break;
        }
    }
    __syncthreads();
    const size_t row0 = (size_t)b * TT + (size_t)tc * 64;
    const int col0 = col * 256;
    const int mt = tid >> 5;
    const int nt = tid & 31;
    const int ar = tid >> 2;
    const int ak = (tid & 3) * 4;
    const float alpha = alpha_p[0];
    const float* bgc  = consts + MEMS;
    float acc[2][2][4][4] = {};
    for (int k0 = 0; k0 < MEMS; k0 += 16) {
        {
            const float4 av = *(const float4*)&W[(row0 + ar) * MEMS + k0 + ak];
            oAs[ak + 0][ar] = av.x; oAs[ak + 1][ar] = av.y;
            oAs[ak + 2][ar] = av.z; oAs[ak + 3][ar] = av.w;
#pragma unroll
            for (int c = 0; c < 4; ++c) {
                const float4 bv  = *(const float4*)&basis[(size_t)(col0 + tid) * SLOTS + k0 + c * 4];
                const float4 bg4 = *(const float4*)&bgc[k0 + c * 4];
                oBs[c * 4 + 0][tid] = bv.x * (alpha * bg4.x);
                oBs[c * 4 + 1][tid] = bv.y * (alpha * bg4.y);
                oBs[c * 4 + 2][tid] = bv.z * (alpha * bg4.z);
                oBs[c * 4 + 3][tid] = bv.w * (alpha * bg4.w);
            }
        }
        __syncthreads();
#pragma unroll
        for (int kk = 0; kk < 16; ++kk) {
            const float4 a0 = *(const float4*)&oAs[kk][mt * 4];
            const float4 a1 = *(const float4*)&oAs[kk][32 + mt * 4];
            const float4 b0 = *(const float4*)&oBs[kk][nt * 4];
            const float4 b1 = *(const float4*)&oBs[kk][128 + nt * 4];
            const float av[2][4] = {{a0.x, a0.y, a0.z, a0.w}, {a1.x, a1.y, a1.z, a1.w}};
            const float bv[2][4] = {{b0.x, b0.y, b0.z, b0.w}, {b1.x, b1.y, b1.z, b1.w}};
#pragma unroll
            for (int p = 0; p < 2; ++p)
#pragma unroll
                for (int q = 0; q < 2; ++q)
#pragma unroll
                    for (int i = 0; i < 4; ++i)
#pragma unroll
                        for (int j = 0; j < 4; ++j)
                            acc[p][q][i][j] += av[p][i] * bv[q][j];
        }
        __syncthreads();
    }
#pragma unroll
    for (int p = 0; p < 2; ++p)
#pragma unroll
        for (int i = 0; i < 4; ++i) {
            const size_t r = row0 + p * 32 + mt * 4 + i;
#pragma unroll
            for (int q = 0; q < 2; ++q) {
                const size_t ro = r * HD + col0 + q * 128 + nt * 4;
                const float4 xv = *(const float4*)&x[ro];
                const float4 o  = {xv.x + acc[p][q][i][0], xv.y + acc[p][q][i][1],
                                   xv.z + acc[p][q][i][2], xv.w + acc[p][q][i][3]};
                *(float4*)&y[ro] = o;
            }
        }
}

// ---------------------------------------------------------------------------
// Fused persistent pipeline.  Blocks 0,1: scan (8 waves).  Blocks 2+:
// workers stealing proj tickets (ascending t; ANY resident subset completes
// them), then outp tickets (gated on scan progress).  Tickets are fetched by
// tid 0 into shared and double-barriered => block-uniform control flow (the
// R4 hang was per-thread tickets entering barriered code divergently).
// Deadlock-freedom needs only blocks 0,1 resident (lowest blockIdx =>
// dispatched first); all spins are bounded regardless.
// ---------------------------------------------------------------------------
__global__ __launch_bounds__(256) void fused_kernel(
    const float* __restrict__ x, const float* __restrict__ basis,
    float* __restrict__ M, float* __restrict__ W, float* __restrict__ y,
    const float* __restrict__ alpha_p, const float* __restrict__ consts,
    int* __restrict__ I,
    const float* __restrict__ ef, const float* __restrict__ es, const float* __restrict__ edg,
    const float* __restrict__ pf, const float* __restrict__ ps, const float* __restrict__ pdg)
{
    if (blockIdx.x < 2) {
        scan_role((int)blockIdx.x * 4 + (threadIdx.x >> 6), M, consts, I,
                  ef, es, edg, pf, ps, pdg, W);
        return;
    }
    __shared__ int tk;
    for (;;) {
        __syncthreads();
        if (threadIdx.x == 0) tk = atomicAdd(&I[I_TICKP], 1);
        __syncthreads();
        const int tile = tk;               // block-uniform
        if (tile >= 512) break;
        proj_topk_tile(tile & 7, tile >> 3, x, basis, M, I, I_MFLAG + tile);
    }
    for (;;) {
        __syncthreads();
        if (threadIdx.x == 0) tk = atomicAdd(&I[I_TICKO], 1);
        __syncthreads();
        const int j = tk;                  // block-uniform
        if (j >= 2048) break;
        outp_tile(j >> 5, (j & 31) >> 2, j & 3, W, basis, x, alpha_p, consts, I, y);
    }
}

// --------------------- sequential fallback wrappers ------------------------
__global__ __launch_bounds__(256) void k_proj(const float* __restrict__ x,
                                              const float* __restrict__ basis,
                                              float* __restrict__ M, int* __restrict__ I)
{
    const int tile = blockIdx.x;
    proj_topk_tile(tile & 7, tile >> 3, x, basis, M, I, I_MFLAG + tile);
}

__global__ __launch_bounds__(256) void k_scan(const float* __restrict__ M,
    const float* __restrict__ consts, int* __restrict__ I,
    const float* __restrict__ ef, const float* __restrict__ es, const float* __restrict__ edg,
    const float* __restrict__ pf, const float* __restrict__ ps, const float* __restrict__ pdg,
    float* __restrict__ W)
{
    scan_role((int)blockIdx.x * 4 + (threadIdx.x >> 6), M, consts, I,
              ef, es, edg, pf, ps, pdg, W);
}

__global__ __launch_bounds__(256) void k_outp(const float* __restrict__ W,
    const float* __restrict__ basis, const float* __restrict__ x,
    const float* __restrict__ alpha_p, const float* __restrict__ consts,
    int* __restrict__ I, float* __restrict__ y)
{
    const int j = blockIdx.x;
    outp_tile(j >> 5, (j & 31) >> 2, j & 3, W, basis, x, alpha_p, consts, I, y);
}

// ---------------------------------------------------------------------------
extern "C" void kernel_launch(void* const* d_in, const int* in_sizes, int n_in,
                              void* d_out, int out_size, void* d_ws, size_t ws_size,
                              hipStream_t stream)
{
    const float* x          = (const float*)d_in[0];
    const float* basis      = (const float*)d_in[1];
    const float* t0re       = (const float*)d_in[2];
    const float* t0im       = (const float*)d_in[3];
    const float* eta_raw    = (const float*)d_in[4];
    const float* alpha      = (const float*)d_in[5];
    const float* trot       = (const float*)d_in[6];
    const float* w_r        = (const float*)d_in[7];
    const float* bgate      = (const float*)d_in[8];
    const float* eps_fac    = (const float*)d_in[9];
    const float* eps_scale  = (const float*)d_in[10];
    const float* eps_diag   = (const float*)d_in[11];
    const float* pred_fac   = (const float*)d_in[12];
    const float* pred_scale = (const float*)d_in[13];
    const float* pred_diag  = (const float*)d_in[14];
    float* out = (float*)d_out;

    const size_t szM = (size_t)RR * MEMS * sizeof(float);  // 32 MB
    const size_t szW = szM;                                 // 32 MB
    const size_t szC = 16384;

    char* ws = (char*)d_ws;
    const bool pipelined = (ws_size >= szM + szW + szC);
    float *Mbuf, *Wbuf, *cbuf;
    if (pipelined) {
        Mbuf = (float*)(ws);
        Wbuf = (float*)(ws + szM);
        cbuf = (float*)(ws + szM + szW);
    } else {
        // sequential fallback: M staged in d_out (fully consumed by scan
        // before outp rewrites d_out with Y).
        Mbuf = (float*)d_out;
        Wbuf = (float*)(ws);
        cbuf = (float*)(ws + szW);
    }
    int* I = (int*)(cbuf + 8 * MEMS + 16);

    prep_kernel<<<1, 256, 0, stream>>>(t0re, t0im, eta_raw, trot, w_r, bgate,
                                       eps_scale, pred_scale, eps_diag, pred_diag,
                                       cbuf, I);
    if (pipelined) {
        fused_kernel<<<512, 256, 0, stream>>>(x, basis, Mbuf, Wbuf, out, alpha,
                                              cbuf, I,
                                              eps_fac, eps_scale, eps_diag,
                                              pred_fac, pred_scale, pred_diag);
    } else {
        k_proj<<<512, 256, 0, stream>>>(x, basis, Mbuf, I);
        k_scan<<<2, 256, 0, stream>>>(Mbuf, cbuf, I,
                                      eps_fac, eps_scale, eps_diag,
                                      pred_fac, pred_scale, pred_diag, Wbuf);
        k_outp<<<2048, 256, 0, stream>>>(Wbuf, basis, x, alpha, cbuf, I, out);
    }
}

// Round 7
// 1039.848 us; speedup vs baseline: 1.3698x; 1.3698x over previous
//
#include <hip/hip_runtime.h>
#include <cstdint>
#include <cstddef>

#define HD    1024
#define SLOTS 272
#define MEMS  256
#define BATCH 8
#define TT    4096
#define RR    (BATCH*TT)
#define RANKC 10

#define GAMMA 0.92f
#define BETA  0.08f
#define PTS   0.4f

typedef float f32x2 __attribute__((ext_vector_type(2)));
#define PKFMA(a, b, c) __builtin_elementwise_fma((a), (b), (c))

// ---------------------------------------------------------------------------
// DPP wave64 sum-allreduce: 6 VALU-speed cross-lane adds + readlane broadcast.
// ---------------------------------------------------------------------------
#define DPP_ADD(v, ctrl, rmask)                                                   \
    v += __int_as_float(__builtin_amdgcn_update_dpp(                              \
        0, __float_as_int(v), (ctrl), (rmask), 0xf, true))

__device__ __forceinline__ float wave_sum_bcast(float v)
{
    DPP_ADD(v, 0xB1,  0xf);   // + lane^1
    DPP_ADD(v, 0x4E,  0xf);   // + lane^2
    DPP_ADD(v, 0x141, 0xf);   // row_half_mirror
    DPP_ADD(v, 0x140, 0xf);   // row_mirror
    DPP_ADD(v, 0x142, 0xa);   // row_bcast15
    DPP_ADD(v, 0x143, 0xc);   // row_bcast31 (lane 63 = total)
    return __int_as_float(__builtin_amdgcn_readlane(__float_as_int(v), 63));
}

// ---------------------------------------------------------------------------
// prep: per-slot constants.
// consts: [0]=wr [256]=bg [512]=A [768]=B [1024]=v0re [1280]=v0im
//         [1536]=cos [1792]=sin [2048]=eta.  flags[2]: eps/pred any-nonzero.
// ---------------------------------------------------------------------------
__global__ void prep_kernel(const float* __restrict__ t0re, const float* __restrict__ t0im,
                            const float* __restrict__ eta_raw,
                            const float* __restrict__ trot, const float* __restrict__ w_r,
                            const float* __restrict__ bgate,
                            const float* __restrict__ eps_scale, const float* __restrict__ pred_scale,
                            const float* __restrict__ eps_diag, const float* __restrict__ pred_diag,
                            float* __restrict__ consts, int* __restrict__ flags)
{
    __shared__ float red[MEMS];
    const int s = threadIdx.x;  // 256 threads
    const float tr = t0re[s], ti = t0im[s];
    red[s] = tr * tr + ti * ti;
    __syncthreads();
    for (int off = 128; off > 0; off >>= 1) {
        if (s < off) red[s] += red[s + off];
        __syncthreads();
    }
    const float nrm = sqrtf(fmaxf(red[0], 1e-16f));
    const float eta = log1pf(expf(eta_raw[0]));
    const float rc = cosf(trot[s]), rs = sinf(trot[s]);
    const float c1 = GAMMA + eta * eps_diag[s];
    const float c2 = PTS * pred_diag[s];
    consts[0 * MEMS + s] = 1.0f / (1.0f + expf(-w_r[s]));
    consts[1 * MEMS + s] = 1.0f / (1.0f + expf(-bgate[s]));
    consts[2 * MEMS + s] = c1 * rc - c2 * rs;   // A
    consts[3 * MEMS + s] = c1 * rs + c2 * rc;   // B
    consts[4 * MEMS + s] = tr / nrm;
    consts[5 * MEMS + s] = ti / nrm;
    consts[6 * MEMS + s] = rc;
    consts[7 * MEMS + s] = rs;
    if (s == 0) {
        consts[8 * MEMS] = eta;
        int f1 = 0, f2 = 0;
        for (int k = 0; k < RANKC; ++k) {
            if (eps_scale[k]  != 0.0f) f1 = 1;
            if (pred_scale[k] != 0.0f) f2 = 1;
        }
        flags[0] = f1;
        flags[1] = f2;
    }
}

// ---------------------------------------------------------------------------
// proj + FUSED top-8 mask (harness-verified in R5):
// M(64 rows x full 256 cols) = X * Q, then per row: kth = 8th-largest |m|
// (dup-counting), M <- (|m|>=kth) ? BETA*m : 0.  Row owned by the 32
// contiguous lanes sharing mt (half-wave; shfl_xor off<=16 stays inside).
// Kills the standalone topk kernel + its 64 MB M round-trip.
// ---------------------------------------------------------------------------
__global__ __launch_bounds__(256) void proj_topk_kernel(const float* __restrict__ x,
                                                        const float* __restrict__ basis,
                                                        float* __restrict__ M)
{
    __shared__ float pAs[16][64];
    __shared__ float pBs[16][260];
    const int tid  = threadIdx.x;
    const size_t row0 = (size_t)blockIdx.x * 64;
    const int mt = tid >> 5;        // 0..7
    const int nt = tid & 31;        // 0..31
    const int ar = tid >> 2;        // 0..63
    const int ak = (tid & 3) * 4;
    const int bk = tid >> 4;        // 0..15
    const int bn = (tid & 15) * 16;
    float acc[2][2][4][4] = {};
    for (int k0 = 0; k0 < HD; k0 += 16) {
        {
            const float4 av = *(const float4*)&x[(row0 + ar) * HD + k0 + ak];
            pAs[ak + 0][ar] = av.x; pAs[ak + 1][ar] = av.y;
            pAs[ak + 2][ar] = av.z; pAs[ak + 3][ar] = av.w;
#pragma unroll
            for (int c = 0; c < 4; ++c) {
                const float4 bv = *(const float4*)&basis[(size_t)(k0 + bk) * SLOTS + bn + c * 4];
                *(float4*)&pBs[bk][bn + c * 4] = bv;
            }
        }
        __syncthreads();
#pragma unroll
        for (int kk = 0; kk < 16; ++kk) {
            const float4 a0 = *(const float4*)&pAs[kk][mt * 4];
            const float4 a1 = *(const float4*)&pAs[kk][32 + mt * 4];
            const float4 b0 = *(const float4*)&pBs[kk][nt * 4];
            const float4 b1 = *(const float4*)&pBs[kk][128 + nt * 4];
            const float av[2][4] = {{a0.x, a0.y, a0.z, a0.w}, {a1.x, a1.y, a1.z, a1.w}};
            const float bv[2][4] = {{b0.x, b0.y, b0.z, b0.w}, {b1.x, b1.y, b1.z, b1.w}};
#pragma unroll
            for (int p = 0; p < 2; ++p)
#pragma unroll
                for (int q = 0; q < 2; ++q)
#pragma unroll
                    for (int i = 0; i < 4; ++i)
#pragma unroll
                        for (int j = 0; j < 4; ++j)
                            acc[p][q][i][j] += av[p][i] * bv[q][j];
        }
        __syncthreads();
    }
#pragma unroll
    for (int p = 0; p < 2; ++p)
#pragma unroll
        for (int i = 0; i < 4; ++i) {
            float v[8], a[8], w8[8];
#pragma unroll
            for (int q = 0; q < 2; ++q)
#pragma unroll
                for (int j = 0; j < 4; ++j) {
                    v[q * 4 + j] = acc[p][q][i][j];
                    a[q * 4 + j] = fabsf(v[q * 4 + j]);
                    w8[q * 4 + j] = a[q * 4 + j];
                }
            float kv = 0.0f;
#pragma unroll
            for (int it = 0; it < 8; ++it) {
                float lm = w8[0]; int li = 0;
#pragma unroll
                for (int e = 1; e < 8; ++e)
                    if (w8[e] > lm) { lm = w8[e]; li = e; }
                float bm = lm; int bi = nt * 8 + li;
#pragma unroll
                for (int off = 1; off < 32; off <<= 1) {
                    float om = __shfl_xor(bm, off);
                    int   oi = __shfl_xor(bi, off);
                    if (om > bm || (om == bm && oi < bi)) { bm = om; bi = oi; }
                }
                kv = bm;
                if ((bi >> 3) == nt) w8[bi & 7] = -1.0f;
            }
            const int r = p * 32 + mt * 4 + i;
#pragma unroll
            for (int q = 0; q < 2; ++q) {
                float4 o;
                o.x = (a[q * 4 + 0] >= kv) ? BETA * v[q * 4 + 0] : 0.0f;
                o.y = (a[q * 4 + 1] >= kv) ? BETA * v[q * 4 + 1] : 0.0f;
                o.z = (a[q * 4 + 2] >= kv) ? BETA * v[q * 4 + 2] : 0.0f;
                o.w = (a[q * 4 + 3] >= kv) ? BETA * v[q * 4 + 3] : 0.0f;
                *(float4*)&M[(row0 + r) * MEMS + q * 128 + nt * 4] = o;
            }
        }
}

// ---------------------------------------------------------------------------
// scan: R2-exact (measured 392us; optimum of 4 tried formulations — per-step
// cost ~= max(chain ~230cy, insts x ~5cy); R2 sits at the balance point).
// One wave per batch, deferred normalization, depth-16 prefetch ring
// (prefetch may read <=16 rows past the slice: valid adjacent memory,
// values unused).
// ---------------------------------------------------------------------------
__global__ __launch_bounds__(64) void scan_kernel(const float* __restrict__ M,
                                                  const float* __restrict__ consts,
                                                  const int* __restrict__ flags,
                                                  const float* __restrict__ eps_fac,
                                                  const float* __restrict__ eps_scale,
                                                  const float* __restrict__ eps_diag,
                                                  const float* __restrict__ pred_fac,
                                                  const float* __restrict__ pred_scale,
                                                  const float* __restrict__ pred_diag,
                                                  float* __restrict__ Wout)
{
    const int b    = blockIdx.x;
    const int lane = threadIdx.x;
    const int s0   = lane * 4;
    const int general = flags[0] | flags[1];
    const size_t base = (size_t)b * TT * MEMS + s0;

    if (!general) {
        // ---------------- FAST PATH (deferred norm) ----------------
        f32x2 wrg[2], A2[2], B2[2];
        f32x2 wre[2], wim[2], qre[2], qim[2];
        {
            const float4 w4 = *(const float4*)&consts[0 * MEMS + s0];
            const float4 a4 = *(const float4*)&consts[2 * MEMS + s0];
            const float4 b4 = *(const float4*)&consts[3 * MEMS + s0];
            const float4 r4 = *(const float4*)&consts[4 * MEMS + s0];
            const float4 i4 = *(const float4*)&consts[5 * MEMS + s0];
            wrg[0] = {w4.x, w4.y};  wrg[1] = {w4.z, w4.w};
            A2[0]  = {a4.x, a4.y};  A2[1]  = {a4.z, a4.w};
            B2[0]  = {b4.x, b4.y};  B2[1]  = {b4.z, b4.w};
            wre[0] = {r4.x, r4.y};  wre[1] = {r4.z, r4.w};
            wim[0] = {i4.x, i4.y};  wim[1] = {i4.z, i4.w};
            qre[0] = wre[0]; qre[1] = wre[1];
            qim[0] = wim[0]; qim[1] = wim[1];
        }
        float ssp;
        {
            const f32x2 p0 = PKFMA(wim[0], wim[0], wre[0] * wre[0]);
            const f32x2 p1 = PKFMA(wim[1], wim[1], wre[1] * wre[1]);
            const f32x2 pp = p0 + p1;
            ssp = pp.x + pp.y;
        }
        float4 mbuf[16];
#pragma unroll
        for (int j = 0; j < 16; ++j)
            mbuf[j] = *(const float4*)&M[base + (size_t)j * MEMS];
        for (int t0 = 0; t0 < TT; t0 += 16) {
#pragma unroll
            for (int j = 0; j < 16; ++j) {
                const int t = t0 + j;
                const float4 mc = mbuf[j];
                mbuf[j] = *(const float4*)&M[base + (size_t)(t + 16) * MEMS];
                const float stot = wave_sum_bcast(ssp);
                const float icv  = __builtin_amdgcn_rsqf(fmaxf(stot, 1e-16f));
                const f32x2 ic2  = {icv, icv};
                const f32x2 Lr0 = PKFMA(A2[0], wre[0], -(B2[0] * wim[0]));
                const f32x2 Li0 = PKFMA(B2[0], wre[0],  A2[0] * wim[0]);
                const f32x2 Lr1 = PKFMA(A2[1], wre[1], -(B2[1] * wim[1]));
                const f32x2 Li1 = PKFMA(B2[1], wre[1],  A2[1] * wim[1]);
                const f32x2 m0 = {mc.x, mc.y};
                const f32x2 m1 = {mc.z, mc.w};
                const f32x2 Wr0 = PKFMA(wrg[0], qre[0], m0);
                const f32x2 Wi0 = wrg[0] * qim[0];
                const f32x2 Wr1 = PKFMA(wrg[1], qre[1], m1);
                const f32x2 Wi1 = wrg[1] * qim[1];
                const f32x2 u1r0 = PKFMA(ic2, Lr0, Wr0);
                const f32x2 u1i0 = PKFMA(ic2, Li0, Wi0);
                const f32x2 u1r1 = PKFMA(ic2, Lr1, Wr1);
                const f32x2 u1i1 = PKFMA(ic2, Li1, Wi1);
                const f32x2 ps0 = PKFMA(u1i0, u1i0, u1r0 * u1r0);
                const f32x2 ps1 = PKFMA(u1i1, u1i1, u1r1 * u1r1);
                const f32x2 pp  = ps0 + ps1;
                const f32x2 nr0 = wre[0] * ic2, ni0 = wim[0] * ic2;
                const f32x2 nr1 = wre[1] * ic2, ni1 = wim[1] * ic2;
                const int trow = t ? (t - 1) : 0;
                const float4 st4 = {nr0.x, nr0.y, nr1.x, nr1.y};
                *(float4*)&Wout[base + (size_t)trow * MEMS] = st4;
                qre[0] = nr0;  qim[0] = ni0;  qre[1] = nr1;  qim[1] = ni1;
                wre[0] = u1r0; wim[0] = u1i0; wre[1] = u1r1; wim[1] = u1i1;
                ssp = pp.x + pp.y;
            }
        }
        {
            const float stot = wave_sum_bcast(ssp);
            const float icv  = __builtin_amdgcn_rsqf(fmaxf(stot, 1e-16f));
            const float4 wq4 = {wre[0].x * icv, wre[0].y * icv,
                                wre[1].x * icv, wre[1].y * icv};
            *(float4*)&Wout[base + (size_t)(TT - 1) * MEMS] = wq4;
        }
        return;
    }

    // ---------------- GENERAL PATH (R2 verbatim) ----------------
    float wr4[4], ur[4], ui[4], pr[4], pi[4];
    float rc4[4], rs4[4], ed4[4], pd4[4];
#pragma unroll
    for (int i = 0; i < 4; ++i) {
        wr4[i] = consts[0 * MEMS + s0 + i];
        ur[i]  = consts[4 * MEMS + s0 + i];
        ui[i]  = consts[5 * MEMS + s0 + i];
        pr[i] = ur[i]; pi[i] = ui[i];
        rc4[i] = consts[6 * MEMS + s0 + i];
        rs4[i] = consts[7 * MEMS + s0 + i];
        ed4[i] = eps_diag[s0 + i];
        pd4[i] = pred_diag[s0 + i];
    }
    const float eta  = consts[8 * MEMS];
    const int es_any = flags[0];
    const int ps_any = flags[1];
    float4 mbuf[4];
#pragma unroll
    for (int j = 0; j < 4; ++j)
        mbuf[j] = *(const float4*)&M[base + (size_t)j * MEMS];
    for (int t0 = 0; t0 < TT; t0 += 4) {
#pragma unroll
        for (int j = 0; j < 4; ++j) {
            const int t = t0 + j;
            const float4 mc = mbuf[j];
            const int pft = (t + 4 < TT) ? (t + 4) : (TT - 1);
            mbuf[j] = *(const float4*)&M[base + (size_t)pft * MEMS];
            float rr[4], ri[4], nr[4], ni[4];
#pragma unroll
            for (int i = 0; i < 4; ++i) {
                rr[i] = ur[i] * rc4[i] - ui[i] * rs4[i];
                ri[i] = ur[i] * rs4[i] + ui[i] * rc4[i];
            }
            const float mv[4] = {mc.x, mc.y, mc.z, mc.w};
#pragma unroll
            for (int i = 0; i < 4; ++i) {
                nr[i] = GAMMA * rr[i] + wr4[i] * pr[i] + eta * ed4[i] * rr[i]
                        - PTS * pd4[i] * ri[i] + mv[i];   // mv already BETA*inj
                ni[i] = GAMMA * ri[i] + wr4[i] * pi[i] + eta * ed4[i] * ri[i]
                        + PTS * pd4[i] * rr[i];
            }
            if (es_any) {
#pragma unroll
                for (int k = 0; k < RANKC; ++k) {
                    float u[4], prj = 0.0f, pij = 0.0f;
#pragma unroll
                    for (int i = 0; i < 4; ++i) {
                        u[i] = eps_fac[(size_t)(s0 + i) * RANKC + k];
                        prj = fmaf(u[i], rr[i], prj);
                        pij = fmaf(u[i], ri[i], pij);
                    }
                    prj = wave_sum_bcast(prj);
                    pij = wave_sum_bcast(pij);
                    const float sc = eta * eps_scale[k];
#pragma unroll
                    for (int i = 0; i < 4; ++i) {
                        nr[i] = fmaf(sc * u[i], prj, nr[i]);
                        ni[i] = fmaf(sc * u[i], pij, ni[i]);
                    }
                }
            }
            if (ps_any) {
#pragma unroll
                for (int k = 0; k < RANKC; ++k) {
                    float u[4], qrj = 0.0f, qij = 0.0f;
#pragma unroll
                    for (int i = 0; i < 4; ++i) {
                        u[i] = pred_fac[(size_t)(s0 + i) * RANKC + k];
                        qrj = fmaf(u[i], rr[i], qrj);
                        qij = fmaf(u[i], ri[i], qij);
                    }
                    qrj = wave_sum_bcast(qrj);
                    qij = wave_sum_bcast(qij);
                    const float sc = PTS * pred_scale[k];
#pragma unroll
                    for (int i = 0; i < 4; ++i) {
                        nr[i] = fmaf(-sc * u[i], qij, nr[i]);
                        ni[i] = fmaf( sc * u[i], qrj, ni[i]);
                    }
                }
            }
            float ss = 0.0f;
#pragma unroll
            for (int i = 0; i < 4; ++i) ss = fmaf(nr[i], nr[i], fmaf(ni[i], ni[i], ss));
            ss = wave_sum_bcast(ss);
            const float inv = __builtin_amdgcn_rsqf(fmaxf(ss, 1e-16f));
#pragma unroll
            for (int i = 0; i < 4; ++i) {
                pr[i] = ur[i]; pi[i] = ui[i];
                ur[i] = nr[i] * inv; ui[i] = ni[i] * inv;
            }
            const float4 wq = {ur[0], ur[1], ur[2], ur[3]};
            *(float4*)&Wout[base + (size_t)t * MEMS] = wq;
        }
    }
}

// ---------------------------------------------------------------------------
// outp: Y = X + W * (alpha * bg[k] * basisT).  64(M) x 256(N) tile, 8x8
// microtile (split 4+4 col fragments) — harness-verified in R3.
// ---------------------------------------------------------------------------
__global__ __launch_bounds__(256) void outp_kernel(const float* __restrict__ W,
                                                   const float* __restrict__ basis,
                                                   const float* __restrict__ x,
                                                   const float* __restrict__ alpha_p,
                                                   const float* __restrict__ consts,
                                                   float* __restrict__ y)
{
    __shared__ float oAs[16][64];    // [k][m]   (k = slot dim)
    __shared__ float oBs[16][260];   // [k][h]
    const int tid  = threadIdx.x;
    const size_t row0 = (size_t)blockIdx.x * 64;
    const int col0 = blockIdx.y * 256;
    const int mt = tid >> 5;
    const int nt = tid & 31;
    const int ar = tid >> 2;
    const int ak = (tid & 3) * 4;
    const float alpha = alpha_p[0];
    const float* bgc  = consts + MEMS;
    float acc[2][2][4][4] = {};
    for (int k0 = 0; k0 < MEMS; k0 += 16) {
        {
            const float4 av = *(const float4*)&W[(row0 + ar) * MEMS + k0 + ak];
            oAs[ak + 0][ar] = av.x; oAs[ak + 1][ar] = av.y;
            oAs[ak + 2][ar] = av.z; oAs[ak + 3][ar] = av.w;
#pragma unroll
            for (int c = 0; c < 4; ++c) {
                const float4 bv  = *(const float4*)&basis[(size_t)(col0 + tid) * SLOTS + k0 + c * 4];
                const float4 bg4 = *(const float4*)&bgc[k0 + c * 4];
                oBs[c * 4 + 0][tid] = bv.x * (alpha * bg4.x);
                oBs[c * 4 + 1][tid] = bv.y * (alpha * bg4.y);
                oBs[c * 4 + 2][tid] = bv.z * (alpha * bg4.z);
                oBs[c * 4 + 3][tid] = bv.w * (alpha * bg4.w);
            }
        }
        __syncthreads();
#pragma unroll
        for (int kk = 0; kk < 16; ++kk) {
            const float4 a0 = *(const float4*)&oAs[kk][mt * 4];
            const float4 a1 = *(const float4*)&oAs[kk][32 + mt * 4];
            const float4 b0 = *(const float4*)&oBs[kk][nt * 4];
            const float4 b1 = *(const float4*)&oBs[kk][128 + nt * 4];
            const float av[2][4] = {{a0.x, a0.y, a0.z, a0.w}, {a1.x, a1.y, a1.z, a1.w}};
            const float bv[2][4] = {{b0.x, b0.y, b0.z, b0.w}, {b1.x, b1.y, b1.z, b1.w}};
#pragma unroll
            for (int p = 0; p < 2; ++p)
#pragma unroll
                for (int q = 0; q < 2; ++q)
#pragma unroll
                    for (int i = 0; i < 4; ++i)
#pragma unroll
                        for (int j = 0; j < 4; ++j)
                            acc[p][q][i][j] += av[p][i] * bv[q][j];
        }
        __syncthreads();
    }
#pragma unroll
    for (int p = 0; p < 2; ++p)
#pragma unroll
        for (int i = 0; i < 4; ++i) {
            const size_t r = row0 + p * 32 + mt * 4 + i;
#pragma unroll
            for (int q = 0; q < 2; ++q) {
                const size_t ro = r * HD + col0 + q * 128 + nt * 4;
                const float4 xv = *(const float4*)&x[ro];
                const float4 o  = {xv.x + acc[p][q][i][0], xv.y + acc[p][q][i][1],
                                   xv.z + acc[p][q][i][2], xv.w + acc[p][q][i][3]};
                *(float4*)&y[ro] = o;
            }
        }
}

// ---------------------------------------------------------------------------
extern "C" void kernel_launch(void* const* d_in, const int* in_sizes, int n_in,
                              void* d_out, int out_size, void* d_ws, size_t ws_size,
                              hipStream_t stream)
{
    const float* x          = (const float*)d_in[0];
    const float* basis      = (const float*)d_in[1];
    const float* t0re       = (const float*)d_in[2];
    const float* t0im       = (const float*)d_in[3];
    const float* eta_raw    = (const float*)d_in[4];
    const float* alpha      = (const float*)d_in[5];
    const float* trot       = (const float*)d_in[6];
    const float* w_r        = (const float*)d_in[7];
    const float* bgate      = (const float*)d_in[8];
    const float* eps_fac    = (const float*)d_in[9];
    const float* eps_scale  = (const float*)d_in[10];
    const float* eps_diag   = (const float*)d_in[11];
    const float* pred_fac   = (const float*)d_in[12];
    const float* pred_scale = (const float*)d_in[13];
    const float* pred_diag  = (const float*)d_in[14];
    float* out = (float*)d_out;

    const size_t szM = (size_t)RR * MEMS * sizeof(float);  // 32 MB
    const size_t szW = szM;                                 // 32 MB
    const size_t szC = 16384;                               // consts + flags

    char* ws = (char*)d_ws;
    float *Mbuf, *Wbuf, *cbuf;
    if (ws_size >= szM + szW + szC) {
        Mbuf = (float*)(ws);
        Wbuf = (float*)(ws + szM);
        cbuf = (float*)(ws + szM + szW);
    } else {
        // fallback: stage M in d_out (fully consumed by scan before outp
        // rewrites d_out with Y).
        Mbuf = (float*)d_out;
        Wbuf = (float*)(ws);
        cbuf = (float*)(ws + szW);
    }
    int* fbuf = (int*)(cbuf + 8 * MEMS + 16);

    prep_kernel<<<1, 256, 0, stream>>>(t0re, t0im, eta_raw, trot, w_r, bgate,
                                       eps_scale, pred_scale, eps_diag, pred_diag,
                                       cbuf, fbuf);
    proj_topk_kernel<<<RR / 64, 256, 0, stream>>>(x, basis, Mbuf);
    scan_kernel<<<BATCH, 64, 0, stream>>>(Mbuf, cbuf, fbuf,
                                          eps_fac, eps_scale, eps_diag,
                                          pred_fac, pred_scale, pred_diag,
                                          Wbuf);
    outp_kernel<<<dim3(RR / 64, HD / 256), 256, 0, stream>>>(Wbuf, basis, x, alpha,
                                                             cbuf, out);
}

// Round 8
// 991.469 us; speedup vs baseline: 1.4366x; 1.0488x over previous
//
#include <hip/hip_runtime.h>
#include <cstdint>
#include <cstddef>

#define HD    1024
#define SLOTS 272
#define MEMS  256
#define BATCH 8
#define TT    4096
#define RR    (BATCH*TT)
#define RANKC 10

#define GAMMA 0.92f
#define BETA  0.08f
#define PTS   0.4f

typedef float f32x2 __attribute__((ext_vector_type(2)));
typedef float f32x4 __attribute__((ext_vector_type(4)));
typedef short bf16x8 __attribute__((ext_vector_type(8)));
#define PKFMA(a, b, c) __builtin_elementwise_fma((a), (b), (c))

// ---------------------------------------------------------------------------
// DPP wave64 sum-allreduce: 6 VALU-speed cross-lane adds + readlane broadcast.
// ---------------------------------------------------------------------------
#define DPP_ADD(v, ctrl, rmask)                                                   \
    v += __int_as_float(__builtin_amdgcn_update_dpp(                              \
        0, __float_as_int(v), (ctrl), (rmask), 0xf, true))

__device__ __forceinline__ float wave_sum_bcast(float v)
{
    DPP_ADD(v, 0xB1,  0xf);   // + lane^1
    DPP_ADD(v, 0x4E,  0xf);   // + lane^2
    DPP_ADD(v, 0x141, 0xf);   // row_half_mirror
    DPP_ADD(v, 0x140, 0xf);   // row_mirror
    DPP_ADD(v, 0x142, 0xa);   // row_bcast15
    DPP_ADD(v, 0x143, 0xc);   // row_bcast31 (lane 63 = total)
    return __int_as_float(__builtin_amdgcn_readlane(__float_as_int(v), 63));
}

// fp32 -> bf16 round-to-nearest-even (bit trick, no header type dependence)
__device__ __forceinline__ unsigned short f2bf(float f)
{
    unsigned u = __float_as_uint(f);
    u = (u + 0x7FFFu + ((u >> 16) & 1u)) >> 16;
    return (unsigned short)u;
}

// ---------------------------------------------------------------------------
// prep: per-slot constants.
// consts: [0]=wr [256]=bg [512]=A [768]=B [1024]=v0re [1280]=v0im
//         [1536]=cos [1792]=sin [2048]=eta.  flags[2]: eps/pred any-nonzero.
// ---------------------------------------------------------------------------
__global__ void prep_kernel(const float* __restrict__ t0re, const float* __restrict__ t0im,
                            const float* __restrict__ eta_raw,
                            const float* __restrict__ trot, const float* __restrict__ w_r,
                            const float* __restrict__ bgate,
                            const float* __restrict__ eps_scale, const float* __restrict__ pred_scale,
                            const float* __restrict__ eps_diag, const float* __restrict__ pred_diag,
                            float* __restrict__ consts, int* __restrict__ flags)
{
    __shared__ float red[MEMS];
    const int s = threadIdx.x;  // 256 threads
    const float tr = t0re[s], ti = t0im[s];
    red[s] = tr * tr + ti * ti;
    __syncthreads();
    for (int off = 128; off > 0; off >>= 1) {
        if (s < off) red[s] += red[s + off];
        __syncthreads();
    }
    const float nrm = sqrtf(fmaxf(red[0], 1e-16f));
    const float eta = log1pf(expf(eta_raw[0]));
    const float rc = cosf(trot[s]), rs = sinf(trot[s]);
    const float c1 = GAMMA + eta * eps_diag[s];
    const float c2 = PTS * pred_diag[s];
    consts[0 * MEMS + s] = 1.0f / (1.0f + expf(-w_r[s]));
    consts[1 * MEMS + s] = 1.0f / (1.0f + expf(-bgate[s]));
    consts[2 * MEMS + s] = c1 * rc - c2 * rs;   // A
    consts[3 * MEMS + s] = c1 * rs + c2 * rc;   // B
    consts[4 * MEMS + s] = tr / nrm;
    consts[5 * MEMS + s] = ti / nrm;
    consts[6 * MEMS + s] = rc;
    consts[7 * MEMS + s] = rs;
    if (s == 0) {
        consts[8 * MEMS] = eta;
        int f1 = 0, f2 = 0;
        for (int k = 0; k < RANKC; ++k) {
            if (eps_scale[k]  != 0.0f) f1 = 1;
            if (pred_scale[k] != 0.0f) f2 = 1;
        }
        flags[0] = f1;
        flags[1] = f2;
    }
}

// ---------------------------------------------------------------------------
// gprep: G[h][k] = bf16(alpha * bg[k] * basis[h][k]), row-major [1024][256].
// Pre-baked bf16 B-operand for the MFMA outp: every B-frag is ONE 16B load.
// ---------------------------------------------------------------------------
__global__ void gprep_kernel(const float* __restrict__ basis,
                             const float* __restrict__ alpha_p,
                             const float* __restrict__ consts,
                             unsigned short* __restrict__ G)
{
    const int h = blockIdx.x;          // 0..1023
    const int k = threadIdx.x;         // 0..255
    const float g = alpha_p[0] * consts[MEMS + k] * basis[(size_t)h * SLOTS + k];
    G[(size_t)h * MEMS + k] = f2bf(g);
}

// ---------------------------------------------------------------------------
// proj + FUSED top-8 mask (harness-verified in R5/R7).  Stays fp32: top-k
// selection is tie-sensitive, bf16 could flip near-degenerate thresholds.
// ---------------------------------------------------------------------------
__global__ __launch_bounds__(256) void proj_topk_kernel(const float* __restrict__ x,
                                                        const float* __restrict__ basis,
                                                        float* __restrict__ M)
{
    __shared__ float pAs[16][64];
    __shared__ float pBs[16][260];
    const int tid  = threadIdx.x;
    const size_t row0 = (size_t)blockIdx.x * 64;
    const int mt = tid >> 5;        // 0..7
    const int nt = tid & 31;        // 0..31
    const int ar = tid >> 2;        // 0..63
    const int ak = (tid & 3) * 4;
    const int bk = tid >> 4;        // 0..15
    const int bn = (tid & 15) * 16;
    float acc[2][2][4][4] = {};
    for (int k0 = 0; k0 < HD; k0 += 16) {
        {
            const float4 av = *(const float4*)&x[(row0 + ar) * HD + k0 + ak];
            pAs[ak + 0][ar] = av.x; pAs[ak + 1][ar] = av.y;
            pAs[ak + 2][ar] = av.z; pAs[ak + 3][ar] = av.w;
#pragma unroll
            for (int c = 0; c < 4; ++c) {
                const float4 bv = *(const float4*)&basis[(size_t)(k0 + bk) * SLOTS + bn + c * 4];
                *(float4*)&pBs[bk][bn + c * 4] = bv;
            }
        }
        __syncthreads();
#pragma unroll
        for (int kk = 0; kk < 16; ++kk) {
            const float4 a0 = *(const float4*)&pAs[kk][mt * 4];
            const float4 a1 = *(const float4*)&pAs[kk][32 + mt * 4];
            const float4 b0 = *(const float4*)&pBs[kk][nt * 4];
            const float4 b1 = *(const float4*)&pBs[kk][128 + nt * 4];
            const float av[2][4] = {{a0.x, a0.y, a0.z, a0.w}, {a1.x, a1.y, a1.z, a1.w}};
            const float bv[2][4] = {{b0.x, b0.y, b0.z, b0.w}, {b1.x, b1.y, b1.z, b1.w}};
#pragma unroll
            for (int p = 0; p < 2; ++p)
#pragma unroll
                for (int q = 0; q < 2; ++q)
#pragma unroll
                    for (int i = 0; i < 4; ++i)
#pragma unroll
                        for (int j = 0; j < 4; ++j)
                            acc[p][q][i][j] += av[p][i] * bv[q][j];
        }
        __syncthreads();
    }
#pragma unroll
    for (int p = 0; p < 2; ++p)
#pragma unroll
        for (int i = 0; i < 4; ++i) {
            float v[8], a[8], w8[8];
#pragma unroll
            for (int q = 0; q < 2; ++q)
#pragma unroll
                for (int j = 0; j < 4; ++j) {
                    v[q * 4 + j] = acc[p][q][i][j];
                    a[q * 4 + j] = fabsf(v[q * 4 + j]);
                    w8[q * 4 + j] = a[q * 4 + j];
                }
            float kv = 0.0f;
#pragma unroll
            for (int it = 0; it < 8; ++it) {
                float lm = w8[0]; int li = 0;
#pragma unroll
                for (int e = 1; e < 8; ++e)
                    if (w8[e] > lm) { lm = w8[e]; li = e; }
                float bm = lm; int bi = nt * 8 + li;
#pragma unroll
                for (int off = 1; off < 32; off <<= 1) {
                    float om = __shfl_xor(bm, off);
                    int   oi = __shfl_xor(bi, off);
                    if (om > bm || (om == bm && oi < bi)) { bm = om; bi = oi; }
                }
                kv = bm;
                if ((bi >> 3) == nt) w8[bi & 7] = -1.0f;
            }
            const int r = p * 32 + mt * 4 + i;
#pragma unroll
            for (int q = 0; q < 2; ++q) {
                float4 o;
                o.x = (a[q * 4 + 0] >= kv) ? BETA * v[q * 4 + 0] : 0.0f;
                o.y = (a[q * 4 + 1] >= kv) ? BETA * v[q * 4 + 1] : 0.0f;
                o.z = (a[q * 4 + 2] >= kv) ? BETA * v[q * 4 + 2] : 0.0f;
                o.w = (a[q * 4 + 3] >= kv) ? BETA * v[q * 4 + 3] : 0.0f;
                *(float4*)&M[(row0 + r) * MEMS + q * 128 + nt * 4] = o;
            }
        }
}

// ---------------------------------------------------------------------------
// scan: R2-exact (measured 387us; chain-bound optimum of tried formulations).
// ---------------------------------------------------------------------------
__global__ __launch_bounds__(64) void scan_kernel(const float* __restrict__ M,
                                                  const float* __restrict__ consts,
                                                  const int* __restrict__ flags,
                                                  const float* __restrict__ eps_fac,
                                                  const float* __restrict__ eps_scale,
                                                  const float* __restrict__ eps_diag,
                                                  const float* __restrict__ pred_fac,
                                                  const float* __restrict__ pred_scale,
                                                  const float* __restrict__ pred_diag,
                                                  float* __restrict__ Wout)
{
    const int b    = blockIdx.x;
    const int lane = threadIdx.x;
    const int s0   = lane * 4;
    const int general = flags[0] | flags[1];
    const size_t base = (size_t)b * TT * MEMS + s0;

    if (!general) {
        // ---------------- FAST PATH (deferred norm) ----------------
        f32x2 wrg[2], A2[2], B2[2];
        f32x2 wre[2], wim[2], qre[2], qim[2];
        {
            const float4 w4 = *(const float4*)&consts[0 * MEMS + s0];
            const float4 a4 = *(const float4*)&consts[2 * MEMS + s0];
            const float4 b4 = *(const float4*)&consts[3 * MEMS + s0];
            const float4 r4 = *(const float4*)&consts[4 * MEMS + s0];
            const float4 i4 = *(const float4*)&consts[5 * MEMS + s0];
            wrg[0] = {w4.x, w4.y};  wrg[1] = {w4.z, w4.w};
            A2[0]  = {a4.x, a4.y};  A2[1]  = {a4.z, a4.w};
            B2[0]  = {b4.x, b4.y};  B2[1]  = {b4.z, b4.w};
            wre[0] = {r4.x, r4.y};  wre[1] = {r4.z, r4.w};
            wim[0] = {i4.x, i4.y};  wim[1] = {i4.z, i4.w};
            qre[0] = wre[0]; qre[1] = wre[1];
            qim[0] = wim[0]; qim[1] = wim[1];
        }
        float ssp;
        {
            const f32x2 p0 = PKFMA(wim[0], wim[0], wre[0] * wre[0]);
            const f32x2 p1 = PKFMA(wim[1], wim[1], wre[1] * wre[1]);
            const f32x2 pp = p0 + p1;
            ssp = pp.x + pp.y;
        }
        float4 mbuf[16];
#pragma unroll
        for (int j = 0; j < 16; ++j)
            mbuf[j] = *(const float4*)&M[base + (size_t)j * MEMS];
        for (int t0 = 0; t0 < TT; t0 += 16) {
#pragma unroll
            for (int j = 0; j < 16; ++j) {
                const int t = t0 + j;
                const float4 mc = mbuf[j];
                mbuf[j] = *(const float4*)&M[base + (size_t)(t + 16) * MEMS];
                const float stot = wave_sum_bcast(ssp);
                const float icv  = __builtin_amdgcn_rsqf(fmaxf(stot, 1e-16f));
                const f32x2 ic2  = {icv, icv};
                const f32x2 Lr0 = PKFMA(A2[0], wre[0], -(B2[0] * wim[0]));
                const f32x2 Li0 = PKFMA(B2[0], wre[0],  A2[0] * wim[0]);
                const f32x2 Lr1 = PKFMA(A2[1], wre[1], -(B2[1] * wim[1]));
                const f32x2 Li1 = PKFMA(B2[1], wre[1],  A2[1] * wim[1]);
                const f32x2 m0 = {mc.x, mc.y};
                const f32x2 m1 = {mc.z, mc.w};
                const f32x2 Wr0 = PKFMA(wrg[0], qre[0], m0);
                const f32x2 Wi0 = wrg[0] * qim[0];
                const f32x2 Wr1 = PKFMA(wrg[1], qre[1], m1);
                const f32x2 Wi1 = wrg[1] * qim[1];
                const f32x2 u1r0 = PKFMA(ic2, Lr0, Wr0);
                const f32x2 u1i0 = PKFMA(ic2, Li0, Wi0);
                const f32x2 u1r1 = PKFMA(ic2, Lr1, Wr1);
                const f32x2 u1i1 = PKFMA(ic2, Li1, Wi1);
                const f32x2 ps0 = PKFMA(u1i0, u1i0, u1r0 * u1r0);
                const f32x2 ps1 = PKFMA(u1i1, u1i1, u1r1 * u1r1);
                const f32x2 pp  = ps0 + ps1;
                const f32x2 nr0 = wre[0] * ic2, ni0 = wim[0] * ic2;
                const f32x2 nr1 = wre[1] * ic2, ni1 = wim[1] * ic2;
                const int trow = t ? (t - 1) : 0;
                const float4 st4 = {nr0.x, nr0.y, nr1.x, nr1.y};
                *(float4*)&Wout[base + (size_t)trow * MEMS] = st4;
                qre[0] = nr0;  qim[0] = ni0;  qre[1] = nr1;  qim[1] = ni1;
                wre[0] = u1r0; wim[0] = u1i0; wre[1] = u1r1; wim[1] = u1i1;
                ssp = pp.x + pp.y;
            }
        }
        {
            const float stot = wave_sum_bcast(ssp);
            const float icv  = __builtin_amdgcn_rsqf(fmaxf(stot, 1e-16f));
            const float4 wq4 = {wre[0].x * icv, wre[0].y * icv,
                                wre[1].x * icv, wre[1].y * icv};
            *(float4*)&Wout[base + (size_t)(TT - 1) * MEMS] = wq4;
        }
        return;
    }

    // ---------------- GENERAL PATH (R2 verbatim) ----------------
    float wr4[4], ur[4], ui[4], pr[4], pi[4];
    float rc4[4], rs4[4], ed4[4], pd4[4];
#pragma unroll
    for (int i = 0; i < 4; ++i) {
        wr4[i] = consts[0 * MEMS + s0 + i];
        ur[i]  = consts[4 * MEMS + s0 + i];
        ui[i]  = consts[5 * MEMS + s0 + i];
        pr[i] = ur[i]; pi[i] = ui[i];
        rc4[i] = consts[6 * MEMS + s0 + i];
        rs4[i] = consts[7 * MEMS + s0 + i];
        ed4[i] = eps_diag[s0 + i];
        pd4[i] = pred_diag[s0 + i];
    }
    const float eta  = consts[8 * MEMS];
    const int es_any = flags[0];
    const int ps_any = flags[1];
    float4 mbuf[4];
#pragma unroll
    for (int j = 0; j < 4; ++j)
        mbuf[j] = *(const float4*)&M[base + (size_t)j * MEMS];
    for (int t0 = 0; t0 < TT; t0 += 4) {
#pragma unroll
        for (int j = 0; j < 4; ++j) {
            const int t = t0 + j;
            const float4 mc = mbuf[j];
            const int pft = (t + 4 < TT) ? (t + 4) : (TT - 1);
            mbuf[j] = *(const float4*)&M[base + (size_t)pft * MEMS];
            float rr[4], ri[4], nr[4], ni[4];
#pragma unroll
            for (int i = 0; i < 4; ++i) {
                rr[i] = ur[i] * rc4[i] - ui[i] * rs4[i];
                ri[i] = ur[i] * rs4[i] + ui[i] * rc4[i];
            }
            const float mv[4] = {mc.x, mc.y, mc.z, mc.w};
#pragma unroll
            for (int i = 0; i < 4; ++i) {
                nr[i] = GAMMA * rr[i] + wr4[i] * pr[i] + eta * ed4[i] * rr[i]
                        - PTS * pd4[i] * ri[i] + mv[i];   // mv already BETA*inj
                ni[i] = GAMMA * ri[i] + wr4[i] * pi[i] + eta * ed4[i] * ri[i]
                        + PTS * pd4[i] * rr[i];
            }
            if (es_any) {
#pragma unroll
                for (int k = 0; k < RANKC; ++k) {
                    float u[4], prj = 0.0f, pij = 0.0f;
#pragma unroll
                    for (int i = 0; i < 4; ++i) {
                        u[i] = eps_fac[(size_t)(s0 + i) * RANKC + k];
                        prj = fmaf(u[i], rr[i], prj);
                        pij = fmaf(u[i], ri[i], pij);
                    }
                    prj = wave_sum_bcast(prj);
                    pij = wave_sum_bcast(pij);
                    const float sc = eta * eps_scale[k];
#pragma unroll
                    for (int i = 0; i < 4; ++i) {
                        nr[i] = fmaf(sc * u[i], prj, nr[i]);
                        ni[i] = fmaf(sc * u[i], pij, ni[i]);
                    }
                }
            }
            if (ps_any) {
#pragma unroll
                for (int k = 0; k < RANKC; ++k) {
                    float u[4], qrj = 0.0f, qij = 0.0f;
#pragma unroll
                    for (int i = 0; i < 4; ++i) {
                        u[i] = pred_fac[(size_t)(s0 + i) * RANKC + k];
                        qrj = fmaf(u[i], rr[i], qrj);
                        qij = fmaf(u[i], ri[i], qij);
                    }
                    qrj = wave_sum_bcast(qrj);
                    qij = wave_sum_bcast(qij);
                    const float sc = PTS * pred_scale[k];
#pragma unroll
                    for (int i = 0; i < 4; ++i) {
                        nr[i] = fmaf(-sc * u[i], qij, nr[i]);
                        ni[i] = fmaf( sc * u[i], qrj, ni[i]);
                    }
                }
            }
            float ss = 0.0f;
#pragma unroll
            for (int i = 0; i < 4; ++i) ss = fmaf(nr[i], nr[i], fmaf(ni[i], ni[i], ss));
            ss = wave_sum_bcast(ss);
            const float inv = __builtin_amdgcn_rsqf(fmaxf(ss, 1e-16f));
#pragma unroll
            for (int i = 0; i < 4; ++i) {
                pr[i] = ur[i]; pi[i] = ui[i];
                ur[i] = nr[i] * inv; ui[i] = ni[i] * inv;
            }
            const float4 wq = {ur[0], ur[1], ur[2], ur[3]};
            *(float4*)&Wout[base + (size_t)t * MEMS] = wq;
        }
    }
}

// ---------------------------------------------------------------------------
// outp (MFMA bf16): Y = X + W * G,  G pre-baked bf16 = alpha*bg[k]*basis[h][k].
// Block = 64 rows x 256 h, 4 waves x (16 rows x 256 h).  Per wave: 8 A-frags
// (W rows, fp32->bf16 once, reused over 16 col-tiles); B-frags are single
// 16B loads from G[h][k] row-major.  mfma_f32_16x16x32_bf16, K-loop = 8.
// Layouts: A lane l = A[m=l&15][k=8*(l>>4)+j] (contiguous-k, matches the
// m97-verified ds_read_b128 frag pattern); B lane l = B[k=8*(l>>4)+j][n=l&15];
// C/D: row=(l>>4)*4+i, col=l&15 [HW-verified m89/m91].
// ---------------------------------------------------------------------------
__global__ __launch_bounds__(256) void outp_kernel(const float* __restrict__ W,
                                                   const unsigned short* __restrict__ G,
                                                   const float* __restrict__ x,
                                                   float* __restrict__ y)
{
    const int tid = threadIdx.x;
    const int w   = tid >> 6;          // wave 0..3
    const int l   = tid & 63;
    const int ln  = l & 15;
    const int lk  = (l >> 4) * 8;      // k base within 32-chunk
    const size_t row0 = (size_t)blockIdx.x * 64 + (size_t)w * 16;
    const int col0 = blockIdx.y * 256;

    // A-frags: 8 chunks of K=32 from this wave's 16 W rows
    bf16x8 af[8];
    {
        const float* wrow = &W[(row0 + ln) * MEMS];
#pragma unroll
        for (int c = 0; c < 8; ++c) {
            const float4 a0 = *(const float4*)&wrow[c * 32 + lk];
            const float4 a1 = *(const float4*)&wrow[c * 32 + lk + 4];
            bf16x8 f;
            f[0] = (short)f2bf(a0.x); f[1] = (short)f2bf(a0.y);
            f[2] = (short)f2bf(a0.z); f[3] = (short)f2bf(a0.w);
            f[4] = (short)f2bf(a1.x); f[5] = (short)f2bf(a1.y);
            f[6] = (short)f2bf(a1.z); f[7] = (short)f2bf(a1.w);
            af[c] = f;
        }
    }
#pragma unroll
    for (int ct = 0; ct < 16; ++ct) {
        const int h = col0 + ct * 16 + ln;
        const unsigned short* grow = &G[(size_t)h * MEMS + lk];
        f32x4 acc = {0.0f, 0.0f, 0.0f, 0.0f};
#pragma unroll
        for (int c = 0; c < 8; ++c) {
            const bf16x8 bf = *(const bf16x8*)&grow[c * 32];
            acc = __builtin_amdgcn_mfma_f32_16x16x32_bf16(af[c], bf, acc, 0, 0, 0);
        }
        const size_t rbase = (row0 + (size_t)((l >> 4) * 4)) * HD + h;
#pragma unroll
        for (int i = 0; i < 4; ++i) {
            const size_t ro = rbase + (size_t)i * HD;
            y[ro] = x[ro] + acc[i];
        }
    }
}

// ---------------------------------------------------------------------------
extern "C" void kernel_launch(void* const* d_in, const int* in_sizes, int n_in,
                              void* d_out, int out_size, void* d_ws, size_t ws_size,
                              hipStream_t stream)
{
    const float* x          = (const float*)d_in[0];
    const float* basis      = (const float*)d_in[1];
    const float* t0re       = (const float*)d_in[2];
    const float* t0im       = (const float*)d_in[3];
    const float* eta_raw    = (const float*)d_in[4];
    const float* alpha      = (const float*)d_in[5];
    const float* trot       = (const float*)d_in[6];
    const float* w_r        = (const float*)d_in[7];
    const float* bgate      = (const float*)d_in[8];
    const float* eps_fac    = (const float*)d_in[9];
    const float* eps_scale  = (const float*)d_in[10];
    const float* eps_diag   = (const float*)d_in[11];
    const float* pred_fac   = (const float*)d_in[12];
    const float* pred_scale = (const float*)d_in[13];
    const float* pred_diag  = (const float*)d_in[14];
    float* out = (float*)d_out;

    const size_t szM = (size_t)RR * MEMS * sizeof(float);   // 32 MB
    const size_t szW = szM;                                  // 32 MB
    const size_t szC = 16384;                                // consts + flags
    const size_t szG = (size_t)HD * MEMS * 2;                // 512 KB bf16 G

    char* ws = (char*)d_ws;
    float *Mbuf, *Wbuf, *cbuf;
    unsigned short* Gbuf;
    if (ws_size >= szM + szW + szC + szG) {
        Mbuf = (float*)(ws);
        Wbuf = (float*)(ws + szM);
        cbuf = (float*)(ws + szM + szW);
        Gbuf = (unsigned short*)(ws + szM + szW + szC);
    } else {
        // fallback: stage M in d_out (fully consumed by scan before outp
        // rewrites d_out with Y).
        Mbuf = (float*)d_out;
        Wbuf = (float*)(ws);
        cbuf = (float*)(ws + szW);
        Gbuf = (unsigned short*)(ws + szW + szC);
    }
    int* fbuf = (int*)(cbuf + 8 * MEMS + 16);

    prep_kernel<<<1, 256, 0, stream>>>(t0re, t0im, eta_raw, trot, w_r, bgate,
                                       eps_scale, pred_scale, eps_diag, pred_diag,
                                       cbuf, fbuf);
    gprep_kernel<<<HD, 256, 0, stream>>>(basis, alpha, cbuf, Gbuf);
    proj_topk_kernel<<<RR / 64, 256, 0, stream>>>(x, basis, Mbuf);
    scan_kernel<<<BATCH, 64, 0, stream>>>(Mbuf, cbuf, fbuf,
                                          eps_fac, eps_scale, eps_diag,
                                          pred_fac, pred_scale, pred_diag,
                                          Wbuf);
    outp_kernel<<<dim3(RR / 64, HD / 256), 256, 0, stream>>>(Wbuf, Gbuf, x, out);
}